// Round 1
// baseline (235.307 us; speedup 1.0000x reference)
//
#include <hip/hip_runtime.h>
#include <hip/hip_bf16.h>
#include <math.h>

#define NCC 80
#define BINS 16
#define NCH 144   // 4*BINS+NC
#define NB 16
#define NG 32
#define NA 8400
#define HW0 6400
#define HW1 1600
#define HW2 400
#define TOPKK 10
#define EPSF 1e-9f

__device__ __forceinline__ void anchor_geom(int n, float& cx, float& cy, float& st){
    if(n < HW0){ int y=n/80, x=n-y*80; st=8.f; cx=(x+0.5f)*8.f; cy=(y+0.5f)*8.f; }
    else if(n < HW0+HW1){ int m=n-HW0; int y=m/40, x=m-y*40; st=16.f; cx=(x+0.5f)*16.f; cy=(y+0.5f)*16.f; }
    else { int m=n-(HW0+HW1); int y=m/20, x=m-y*20; st=32.f; cx=(x+0.5f)*32.f; cy=(y+0.5f)*32.f; }
}

__device__ __forceinline__ const float* level_base(const float* p0, const float* p1, const float* p2,
                                                   int b, int n, int& m, int& hw){
    if(n < HW0){ m=n; hw=HW0; return p0 + (size_t)b*NCH*HW0; }
    if(n < HW0+HW1){ m=n-HW0; hw=HW1; return p1 + (size_t)b*NCH*HW1; }
    m=n-(HW0+HW1); hw=HW2; return p2 + (size_t)b*NCH*HW2;
}

__device__ __forceinline__ float iou_gp(float gx1,float gy1,float gx2,float gy2, float4 p){
    float ltx = fmaxf(gx1, p.x), lty = fmaxf(gy1, p.y);
    float rbx = fminf(gx2, p.z), rby = fminf(gy2, p.w);
    float w = fmaxf(rbx-ltx, 0.f), h = fmaxf(rby-lty, 0.f);
    float inter = w*h;
    float ag = (gx2-gx1)*(gy2-gy1);
    float ap = fmaxf(p.z-p.x,0.f)*fmaxf(p.w-p.y,0.f);
    return inter/(ag+ap-inter+EPSF);
}

// ---------------- kernel 1: DFL softmax decode -> pred boxes ----------------
__global__ __launch_bounds__(256) void k_decode(const float* __restrict__ p0, const float* __restrict__ p1,
                                                const float* __restrict__ p2, float4* __restrict__ boxes){
    int n = blockIdx.x*256 + threadIdx.x;
    int b = blockIdx.y;
    if(n >= NA) return;
    int m, hw; const float* base = level_base(p0,p1,p2,b,n,m,hw);
    float cx, cy, st; anchor_geom(n,cx,cy,st);
    float d[4];
    #pragma unroll
    for(int j=0;j<4;j++){
        float v[BINS]; float mx=-1e30f;
        #pragma unroll
        for(int k=0;k<BINS;k++){ v[k]=base[(size_t)(j*BINS+k)*hw + m]; mx = fmaxf(mx, v[k]); }
        float s=0.f, acc=0.f;
        #pragma unroll
        for(int k=0;k<BINS;k++){ float e=expf(v[k]-mx); s+=e; acc+=e*(float)k; }
        d[j] = acc/s*st;
    }
    boxes[(size_t)b*NA + n] = make_float4(cx-d[0], cy-d[1], cx+d[2], cy+d[3]);
}

// ---------------- kernel 2: TAL metric + top-10 per (b,g) ----------------
__global__ __launch_bounds__(256) void k_assign(const float* __restrict__ p0, const float* __restrict__ p1,
                                                const float* __restrict__ p2, const float4* __restrict__ boxes,
                                                const float* __restrict__ gtb, const int* __restrict__ gtl,
                                                unsigned* __restrict__ maskg){
    __shared__ float metric[NA];
    __shared__ float rv[256];
    __shared__ int   ri[256];
    int g = blockIdx.x, b = blockIdx.y, tid = threadIdx.x;
    const float* gb = gtb + ((size_t)b*NG + g)*4;
    float gx1=gb[0], gy1=gb[1], gx2=gb[2], gy2=gb[3];
    int label = gtl[b*NG+g];

    for(int n=tid; n<NA; n+=256){
        float4 pb = boxes[(size_t)b*NA + n];
        float ov = iou_gp(gx1,gy1,gx2,gy2,pb);
        float cx,cy,st; anchor_geom(n,cx,cy,st);
        bool in = (cx>gx1)&&(cx<gx2)&&(cy>gy1)&&(cy<gy2);
        float met = 0.f;
        if(in){
            int m,hw; const float* base = level_base(p0,p1,p2,b,n,m,hw);
            float x = base[(size_t)(4*BINS+label)*hw + m];
            float s = 1.f/(1.f+expf(-x));
            float ov2 = ov*ov;
            met = sqrtf(s) * (ov2*ov2*ov2);
        }
        metric[n] = met;
    }
    __syncthreads();

    for(int k=0;k<TOPKK;k++){
        float bv = -1.f; int bi = 0x7fffffff;
        for(int n=tid; n<NA; n+=256){
            float v = metric[n];
            if(v > bv){ bv=v; bi=n; }   // ascending scan keeps lowest index on ties
        }
        rv[tid]=bv; ri[tid]=bi;
        __syncthreads();
        for(int s=128;s>0;s>>=1){
            if(tid<s){
                if(rv[tid+s]>rv[tid] || (rv[tid+s]==rv[tid] && ri[tid+s]<ri[tid])){
                    rv[tid]=rv[tid+s]; ri[tid]=ri[tid+s];
                }
            }
            __syncthreads();
        }
        float best = rv[0]; int bidx = ri[0];
        if(best <= EPSF) break;          // uniform decision (everyone read rv[0])
        if(tid==0){
            atomicOr(&maskg[(size_t)b*NA + bidx], 1u<<g);
            metric[bidx] = -1.f;
        }
        __syncthreads();
    }
}

// ---------------- kernel 3: resolve multi-assignment, per-(b,g) maxima, fg count ----------------
__global__ __launch_bounds__(256) void k_resolve(const float* __restrict__ p0, const float* __restrict__ p1,
                                                 const float* __restrict__ p2, const float4* __restrict__ boxes,
                                                 const float* __restrict__ gtb, const int* __restrict__ gtl,
                                                 const unsigned* __restrict__ maskg,
                                                 int* __restrict__ matched, float* __restrict__ alignv,
                                                 float* __restrict__ amax, float* __restrict__ omax,
                                                 int* __restrict__ fgcnt){
    __shared__ float sgt[NG*4];
    __shared__ int scnt;
    int tid = threadIdx.x; int b = blockIdx.y;
    if(tid < NG*4) sgt[tid] = gtb[(size_t)b*NG*4 + tid];
    if(tid==0) scnt = 0;
    __syncthreads();
    int n = blockIdx.x*256 + tid;
    if(n < NA){
        int match = -1; float av = 0.f;
        unsigned mask = maskg[(size_t)b*NA + n];
        if(mask){
            float4 pb = boxes[(size_t)b*NA+n];
            float ov;
            if(__popc(mask) > 1){
                float best = -1.f; int bi = 0;
                for(int g=0; g<NG; g++){
                    float o = iou_gp(sgt[g*4],sgt[g*4+1],sgt[g*4+2],sgt[g*4+3],pb);
                    if(o > best){ best=o; bi=g; }   // strict > : first max, matches jnp.argmax
                }
                match = bi; ov = best;
            } else {
                match = __ffs(mask)-1;
                ov = iou_gp(sgt[match*4],sgt[match*4+1],sgt[match*4+2],sgt[match*4+3],pb);
            }
            int label = gtl[b*NG+match];
            int m,hw; const float* base = level_base(p0,p1,p2,b,n,m,hw);
            float x = base[(size_t)(4*BINS+label)*hw + m];
            float s = 1.f/(1.f+expf(-x));
            float ov2 = ov*ov;
            av = sqrtf(s)*(ov2*ov2*ov2);
            atomicMax((int*)&amax[b*NG+match], __float_as_int(av));  // vals >= 0
            atomicMax((int*)&omax[b*NG+match], __float_as_int(ov));
            atomicAdd(&scnt, 1);
        }
        matched[(size_t)b*NA+n] = match;
        alignv[(size_t)b*NA+n]  = av;
    }
    __syncthreads();
    if(tid==0 && scnt) atomicAdd(fgcnt, scnt);
}

// ---------------- kernel 4: the three loss sums ----------------
__global__ __launch_bounds__(256) void k_losses(const float* __restrict__ p0, const float* __restrict__ p1,
                                                const float* __restrict__ p2, const float4* __restrict__ boxes,
                                                const float* __restrict__ gtb, const int* __restrict__ gtl,
                                                const int* __restrict__ matched, const float* __restrict__ alignv,
                                                const float* __restrict__ amax, const float* __restrict__ omax,
                                                float* __restrict__ sums){
    __shared__ float red[256];
    int tid = threadIdx.x, b = blockIdx.y;
    int n = blockIdx.x*256 + tid;
    float iou_l = 0.f, dfl_l = 0.f, cls_l = 0.f;
    if(n < NA){
        int m,hw; const float* base = level_base(p0,p1,p2,b,n,m,hw);
        float cx,cy,st; anchor_geom(n,cx,cy,st);
        int match = matched[(size_t)b*NA+n];
        int tl = -1; float norm = 0.f;
        if(match >= 0){
            float am = amax[b*NG+match], om = omax[b*NG+match];
            norm = alignv[(size_t)b*NA+n]*om/(am+EPSF);
            tl = gtl[b*NG+match];
            const float* gb = gtb + ((size_t)b*NG+match)*4;
            float tx1=gb[0], ty1=gb[1], tx2=gb[2], ty2=gb[3];
            float4 pb = boxes[(size_t)b*NA+n];
            // CIoU
            float w1=pb.z-pb.x, h1=pb.w-pb.y, w2=tx2-tx1, h2=ty2-ty1;
            float inter = fmaxf(fminf(pb.z,tx2)-fmaxf(pb.x,tx1),0.f) *
                          fmaxf(fminf(pb.w,ty2)-fmaxf(pb.y,ty1),0.f);
            float uni = w1*h1 + w2*h2 - inter + EPSF;
            float iou = inter/uni;
            float cwd = fmaxf(pb.z,tx2)-fminf(pb.x,tx1);
            float chd = fmaxf(pb.w,ty2)-fminf(pb.y,ty1);
            float c2 = cwd*cwd + chd*chd + EPSF;
            float dx = pb.x+pb.z-tx1-tx2, dy = pb.y+pb.w-ty1-ty2;
            float rho2 = (dx*dx + dy*dy)*0.25f;
            float dv = atanf(w2/(h2+EPSF)) - atanf(w1/(h1+EPSF));
            float v = 0.40528473456935108577f*dv*dv;   // 4/pi^2
            float alpha = v/(v - iou + 1.f + EPSF);
            iou_l = 1.f - (iou - rho2/c2 - v*alpha);
            // DFL
            float dt4[4] = { fmaxf(cx-tx1,0.f), fmaxf(cy-ty1,0.f), fmaxf(tx2-cx,0.f), fmaxf(ty2-cy,0.f) };
            #pragma unroll
            for(int j=0;j<4;j++){
                float d = fminf(fmaxf(dt4[j]/st, 0.f), 14.999999f);
                float lo = floorf(d);
                float a = d - lo;
                int li = (int)lo; int ui = min(li+1, BINS-1);
                float vbuf[BINS]; float mx = -1e30f;
                #pragma unroll
                for(int k=0;k<BINS;k++){ float vv = base[(size_t)(j*BINS+k)*hw + m]; vbuf[k]=vv; mx=fmaxf(mx,vv); }
                float sse = 0.f, xlo = 0.f, xup = 0.f;
                #pragma unroll
                for(int k=0;k<BINS;k++){
                    sse += expf(vbuf[k]-mx);
                    if(k==li) xlo = vbuf[k];
                    if(k==ui) xup = vbuf[k];
                }
                float lse = mx + logf(sse);
                dfl_l += -((1.f-a)*(xlo-lse) + a*(xup-lse));
            }
        }
        // cls focal over 80 classes (every anchor)
        #pragma unroll 4
        for(int c=0;c<NCC;c++){
            float x = base[(size_t)(4*BINS+c)*hw + m];
            float t = (c==tl) ? norm : 0.f;
            float p = 1.f/(1.f+expf(-x));
            float ce = fmaxf(x,0.f) - x*t + log1pf(expf(-fabsf(x)));
            float pt = p*t + (1.f-p)*(1.f-t);
            float at = t*0.25f + (1.f-t)*0.75f;
            float ompt = 1.f - pt;
            cls_l += at*ompt*ompt*ce;
        }
    }
    // block reductions + one atomic each
    red[tid]=iou_l; __syncthreads();
    for(int s=128;s>0;s>>=1){ if(tid<s) red[tid]+=red[tid+s]; __syncthreads(); }
    if(tid==0) atomicAdd(&sums[0], red[0]);
    __syncthreads();
    red[tid]=dfl_l; __syncthreads();
    for(int s=128;s>0;s>>=1){ if(tid<s) red[tid]+=red[tid+s]; __syncthreads(); }
    if(tid==0) atomicAdd(&sums[1], red[0]);
    __syncthreads();
    red[tid]=cls_l; __syncthreads();
    for(int s=128;s>0;s>>=1){ if(tid<s) red[tid]+=red[tid+s]; __syncthreads(); }
    if(tid==0) atomicAdd(&sums[2], red[0]);
}

// ---------------- kernel 5: finalize ----------------
__global__ void k_final(const float* __restrict__ sums, const int* __restrict__ cnt, float* __restrict__ out){
    int c = *cnt;
    float den = (float)(c > 1 ? c : 1);
    out[0] = 7.5f * sums[0] / den;
    out[1] = 1.5f * sums[1] / den;
    out[2] = 0.5f * sums[2] / den;
}

extern "C" void kernel_launch(void* const* d_in, const int* in_sizes, int n_in,
                              void* d_out, int out_size, void* d_ws, size_t ws_size,
                              hipStream_t stream) {
    (void)in_sizes; (void)n_in; (void)out_size; (void)ws_size;
    const float* p0  = (const float*)d_in[0];
    const float* p1  = (const float*)d_in[1];
    const float* p2  = (const float*)d_in[2];
    const float* gtb = (const float*)d_in[3];
    const int*   gtl = (const int*)d_in[4];
    float* out = (float*)d_out;

    char* ws = (char*)d_ws;
    // layout: [sums 3f][cnt 1i][amax 512f][omax 512f][maskg B*N u32] | boxes | matched | alignv
    float*    sums   = (float*)   (ws + 0);
    int*      cnt    = (int*)     (ws + 12);
    float*    amax   = (float*)   (ws + 16);
    float*    omax   = (float*)   (ws + 16 + 2048);
    unsigned* maskg  = (unsigned*)(ws + 16 + 4096);                      // B*N u32 = 537600 B
    size_t zbytes    = 16 + 4096 + (size_t)NB*NA*4;                      // = 541712 (16-aligned)
    float4*   boxes  = (float4*)  (ws + zbytes);                         // B*N*16 B = 2150400
    int*      matched= (int*)     (ws + zbytes + (size_t)NB*NA*16);
    float*    alignv = (float*)   (ws + zbytes + (size_t)NB*NA*16 + (size_t)NB*NA*4);

    hipMemsetAsync(ws, 0, zbytes, stream);

    dim3 blk(256);
    dim3 ga((NA + 255)/256, NB);   // 33 x 16
    k_decode <<<ga,          blk, 0, stream>>>(p0,p1,p2, boxes);
    k_assign <<<dim3(NG,NB), blk, 0, stream>>>(p0,p1,p2, boxes, gtb, gtl, maskg);
    k_resolve<<<ga,          blk, 0, stream>>>(p0,p1,p2, boxes, gtb, gtl, maskg, matched, alignv, amax, omax, cnt);
    k_losses <<<ga,          blk, 0, stream>>>(p0,p1,p2, boxes, gtb, gtl, matched, alignv, amax, omax, sums);
    k_final  <<<1, 1,             0, stream>>>(sums, cnt, out);
}